// Round 1
// baseline (269.099 us; speedup 1.0000x reference)
//
#include <hip/hip_runtime.h>
#include <hip/hip_bf16.h>

#define B_   2
#define S_   2048
#define D_   768
#define H_   12
#define DK_  64
#define R_   (B_*S_)   // 4096 rows total

typedef __attribute__((ext_vector_type(8))) short short8;
typedef __attribute__((ext_vector_type(4))) float f32x4;

__device__ __forceinline__ short f2b(float f) {
  union { float f; unsigned u; } x; x.f = f;
  unsigned r = x.u + 0x7fffu + ((x.u >> 16) & 1u);
  return (short)(r >> 16);
}

__device__ __forceinline__ void gl_lds16(const short* g, short* l) {
  __builtin_amdgcn_global_load_lds(
      (const __attribute__((address_space(1))) void*)g,
      (__attribute__((address_space(3))) void*)l, 16, 0, 0);
}

// ---------------- fp32 -> bf16 conversion (x + 4 weights) ----------------
__global__ void cvt_kernel(const float* __restrict__ x,
                           const float* __restrict__ wq, const float* __restrict__ wk,
                           const float* __restrict__ wv, const float* __restrict__ wo,
                           short* __restrict__ xb, short* __restrict__ wb) {
  const int XQ = R_ * D_ / 4;   // float4 count for x
  const int WQ = D_ * D_ / 4;   // float4 count per weight
  int idx = blockIdx.x * blockDim.x + threadIdx.x;
  const float* src; short* dst; int off;
  if (idx < XQ) { src = x; dst = xb; off = idx; }
  else {
    int wi = idx - XQ; int w = wi / WQ; off = wi - w * WQ;
    if      (w == 0) { src = wq; dst = wb; }
    else if (w == 1) { src = wk; dst = wb + D_*D_; }
    else if (w == 2) { src = wv; dst = wb + 2*D_*D_; }
    else             { src = wo; dst = wb + 3*D_*D_; }
  }
  float4 v = ((const float4*)src)[off];
  short4 o;
  o.x = f2b(v.x); o.y = f2b(v.y); o.z = f2b(v.z); o.w = f2b(v.w);
  ((short4*)dst)[off] = o;
}

// ---------------- QKV projection: y = x @ W^T + b, head-major outputs ----------------
// 128x128 tile, BK=32, 4 waves (2x2 of 64x64), 16x16x32 bf16 MFMA.
__launch_bounds__(256)
__global__ void qkv_gemm_kernel(const short* __restrict__ xb, const short* __restrict__ wb,
                                const float* __restrict__ bq, const float* __restrict__ bk,
                                const float* __restrict__ bv,
                                short* __restrict__ Qw, short* __restrict__ Kw,
                                short* __restrict__ VTw) {
  __shared__ short As[128 * 32];
  __shared__ short Bs[128 * 32];
  const int which = blockIdx.z;
  const short* W = wb + which * (D_ * D_);
  const float* bias = (which == 0) ? bq : (which == 1) ? bk : bv;
  const int n0 = blockIdx.x * 128, m0 = blockIdx.y * 128;
  const int t = threadIdx.x, l = t & 63, w = t >> 6;
  const int wr = w >> 1, wc = w & 1;

  f32x4 acc[4][4] = {};

  const int srow = t >> 2, sseg = (t & 3) * 8;   // staging: 4x16B units per 32-col row

  for (int k0 = 0; k0 < D_; k0 += 32) {
    __syncthreads();
    gl_lds16(xb + (m0 + srow) * D_ + k0 + sseg,      &As[t * 8]);
    gl_lds16(xb + (m0 + 64 + srow) * D_ + k0 + sseg, &As[(t + 256) * 8]);
    gl_lds16(W  + (n0 + srow) * D_ + k0 + sseg,      &Bs[t * 8]);
    gl_lds16(W  + (n0 + 64 + srow) * D_ + k0 + sseg, &Bs[(t + 256) * 8]);
    __syncthreads();
    short8 a[4], b[4];
#pragma unroll
    for (int i = 0; i < 4; i++)
      a[i] = *(const short8*)&As[(wr * 64 + i * 16 + (l & 15)) * 32 + (l >> 4) * 8];
#pragma unroll
    for (int i = 0; i < 4; i++)
      b[i] = *(const short8*)&Bs[(wc * 64 + i * 16 + (l & 15)) * 32 + (l >> 4) * 8];
#pragma unroll
    for (int i = 0; i < 4; i++)
#pragma unroll
      for (int j = 0; j < 4; j++)
        acc[i][j] = __builtin_amdgcn_mfma_f32_16x16x32_bf16(a[i], b[j], acc[i][j], 0, 0, 0);
  }

  // epilogue: + bias, scatter to head-major layouts (Q pre-scaled by 1/8)
#pragma unroll
  for (int i = 0; i < 4; i++) {
#pragma unroll
    for (int j2 = 0; j2 < 4; j2++) {
      int mm = m0 + wr * 64 + i * 16 + (l >> 4) * 4 + j2;
      int bidx = mm >> 11, s = mm & 2047;
#pragma unroll
      for (int nj = 0; nj < 4; nj++) {
        int e = n0 + wc * 64 + nj * 16 + (l & 15);
        float val = acc[i][nj][j2] + bias[e];
        int h = e >> 6, dk = e & 63;
        int bh = bidx * H_ + h;
        if (which == 0)      Qw[(bh * S_ + s) * DK_ + dk] = f2b(val * 0.125f);
        else if (which == 1) Kw[(bh * S_ + s) * DK_ + dk] = f2b(val);
        else                 VTw[(bh * DK_ + dk) * S_ + s] = f2b(val);
      }
    }
  }
}

// ---------------- flash attention: per (b,h), 128 q-rows/block, 4 waves ----------------
__launch_bounds__(256)
__global__ void attn_kernel(const short* __restrict__ Qw, const short* __restrict__ Kw,
                            const short* __restrict__ VTw, short* __restrict__ ctx) {
  __shared__ short P_lds[4][32 * 136];   // per-wave 32x128 P tile, row padded to 136
  const int t = threadIdx.x, l = t & 63, w = t >> 6;
  const int bh = blockIdx.y;
  const int q0 = blockIdx.x * 128 + w * 32;
  const int bq = bh / H_, h = bh - bq * H_;
  const short* Qh = Qw + bh * S_ * DK_;
  const short* Kh = Kw + bh * S_ * DK_;
  const short* Vh = VTw + bh * DK_ * S_;
  short* pl = &P_lds[w][0];

  // Q fragments live in registers for the whole kernel (scaled by 1/8 already)
  short8 qf[2][2];
#pragma unroll
  for (int mi = 0; mi < 2; mi++)
#pragma unroll
    for (int ks = 0; ks < 2; ks++)
      qf[mi][ks] = *(const short8*)&Qh[(q0 + mi * 16 + (l & 15)) * DK_ + ks * 32 + (l >> 4) * 8];

  f32x4 acc_o[2][4] = {};
  float m_run[2][4], l_run[2][4];
#pragma unroll
  for (int mi = 0; mi < 2; mi++)
#pragma unroll
    for (int j = 0; j < 4; j++) { m_run[mi][j] = -INFINITY; l_run[mi][j] = 0.f; }

  for (int kt = 0; kt < S_; kt += 128) {
    // ---- scores tile: 32 q x 128 k per wave ----
    f32x4 acc_s[2][8] = {};
#pragma unroll
    for (int ni = 0; ni < 8; ni++) {
#pragma unroll
      for (int ks = 0; ks < 2; ks++) {
        short8 kf = *(const short8*)&Kh[(kt + ni * 16 + (l & 15)) * DK_ + ks * 32 + (l >> 4) * 8];
#pragma unroll
        for (int mi = 0; mi < 2; mi++)
          acc_s[mi][ni] = __builtin_amdgcn_mfma_f32_16x16x32_bf16(qf[mi][ks], kf, acc_s[mi][ni], 0, 0, 0);
      }
    }
    // ---- online softmax ----
#pragma unroll
    for (int mi = 0; mi < 2; mi++) {
#pragma unroll
      for (int j = 0; j < 4; j++) {
        float mx = acc_s[mi][0][j];
#pragma unroll
        for (int ni = 1; ni < 8; ni++) mx = fmaxf(mx, acc_s[mi][ni][j]);
#pragma unroll
        for (int d = 1; d < 16; d <<= 1) mx = fmaxf(mx, __shfl_xor(mx, d));
        float mnew = fmaxf(m_run[mi][j], mx);
        float fac = __expf(m_run[mi][j] - mnew);
        m_run[mi][j] = mnew;
        float sum = 0.f;
#pragma unroll
        for (int ni = 0; ni < 8; ni++) {
          float p = __expf(acc_s[mi][ni][j] - mnew);
          acc_s[mi][ni][j] = p;
          sum += p;
        }
#pragma unroll
        for (int d = 1; d < 16; d <<= 1) sum += __shfl_xor(sum, d);
        l_run[mi][j] = l_run[mi][j] * fac + sum;
#pragma unroll
        for (int nd = 0; nd < 4; nd++) acc_o[mi][nd][j] *= fac;
      }
    }
    // ---- P -> LDS (C-layout write), re-read as A fragments (wave-private, no barrier) ----
#pragma unroll
    for (int mi = 0; mi < 2; mi++)
#pragma unroll
      for (int ni = 0; ni < 8; ni++)
#pragma unroll
        for (int j = 0; j < 4; j++)
          pl[(mi * 16 + (l >> 4) * 4 + j) * 136 + ni * 16 + (l & 15)] = f2b(acc_s[mi][ni][j]);
    // ---- PV: ctx += P @ V^T(stored d-major) ----
#pragma unroll
    for (int ks = 0; ks < 4; ks++) {
      short8 pa[2];
#pragma unroll
      for (int mi = 0; mi < 2; mi++)
        pa[mi] = *(const short8*)&pl[(mi * 16 + (l & 15)) * 136 + ks * 32 + (l >> 4) * 8];
#pragma unroll
      for (int nd = 0; nd < 4; nd++) {
        short8 vf = *(const short8*)&Vh[(nd * 16 + (l & 15)) * S_ + kt + ks * 32 + (l >> 4) * 8];
#pragma unroll
        for (int mi = 0; mi < 2; mi++)
          acc_o[mi][nd] = __builtin_amdgcn_mfma_f32_16x16x32_bf16(pa[mi], vf, acc_o[mi][nd], 0, 0, 0);
      }
    }
  }
  // ---- finalize: /l, write ctx [B,S,D] bf16 ----
#pragma unroll
  for (int mi = 0; mi < 2; mi++) {
#pragma unroll
    for (int j = 0; j < 4; j++) {
      float inv = 1.f / l_run[mi][j];
      int s = q0 + mi * 16 + (l >> 4) * 4 + j;
#pragma unroll
      for (int nd = 0; nd < 4; nd++)
        ctx[(bq * S_ + s) * D_ + h * DK_ + nd * 16 + (l & 15)] = f2b(acc_o[mi][nd][j] * inv);
    }
  }
}

// ---------------- output projection: out = ctx @ Wo^T + bo (fp32 out) ----------------
__launch_bounds__(256)
__global__ void oproj_kernel(const short* __restrict__ ctx, const short* __restrict__ Wo,
                             const float* __restrict__ bo, float* __restrict__ out) {
  __shared__ short As[128 * 32];
  __shared__ short Bs[128 * 32];
  const int n0 = blockIdx.x * 128, m0 = blockIdx.y * 128;
  const int t = threadIdx.x, l = t & 63, w = t >> 6;
  const int wr = w >> 1, wc = w & 1;

  f32x4 acc[4][4] = {};
  const int srow = t >> 2, sseg = (t & 3) * 8;

  for (int k0 = 0; k0 < D_; k0 += 32) {
    __syncthreads();
    gl_lds16(ctx + (m0 + srow) * D_ + k0 + sseg,      &As[t * 8]);
    gl_lds16(ctx + (m0 + 64 + srow) * D_ + k0 + sseg, &As[(t + 256) * 8]);
    gl_lds16(Wo  + (n0 + srow) * D_ + k0 + sseg,      &Bs[t * 8]);
    gl_lds16(Wo  + (n0 + 64 + srow) * D_ + k0 + sseg, &Bs[(t + 256) * 8]);
    __syncthreads();
    short8 a[4], b[4];
#pragma unroll
    for (int i = 0; i < 4; i++)
      a[i] = *(const short8*)&As[(wr * 64 + i * 16 + (l & 15)) * 32 + (l >> 4) * 8];
#pragma unroll
    for (int i = 0; i < 4; i++)
      b[i] = *(const short8*)&Bs[(wc * 64 + i * 16 + (l & 15)) * 32 + (l >> 4) * 8];
#pragma unroll
    for (int i = 0; i < 4; i++)
#pragma unroll
      for (int j = 0; j < 4; j++)
        acc[i][j] = __builtin_amdgcn_mfma_f32_16x16x32_bf16(a[i], b[j], acc[i][j], 0, 0, 0);
  }

#pragma unroll
  for (int i = 0; i < 4; i++) {
#pragma unroll
    for (int j2 = 0; j2 < 4; j2++) {
      int mm = m0 + wr * 64 + i * 16 + (l >> 4) * 4 + j2;
#pragma unroll
      for (int nj = 0; nj < 4; nj++) {
        int e = n0 + wc * 64 + nj * 16 + (l & 15);
        out[mm * D_ + e] = acc[i][nj][j2] + bo[e];
      }
    }
  }
}

extern "C" void kernel_launch(void* const* d_in, const int* in_sizes, int n_in,
                              void* d_out, int out_size, void* d_ws, size_t ws_size,
                              hipStream_t stream) {
  (void)in_sizes; (void)n_in; (void)out_size; (void)ws_size;
  const float* x  = (const float*)d_in[0];
  const float* wq = (const float*)d_in[1];
  const float* bq = (const float*)d_in[2];
  const float* wk = (const float*)d_in[3];
  const float* bk = (const float*)d_in[4];
  const float* wv = (const float*)d_in[5];
  const float* bv = (const float*)d_in[6];
  const float* wo = (const float*)d_in[7];
  const float* bo = (const float*)d_in[8];
  float* out = (float*)d_out;

  short* xb  = (short*)d_ws;            // R*D bf16
  short* wb  = xb + R_ * D_;            // 4*D*D bf16 (q,k,v,o)
  short* Qw  = wb + 4 * D_ * D_;        // [B,H,S,DK]
  short* Kw  = Qw + R_ * D_;            // [B,H,S,DK]
  short* VTw = Kw + R_ * D_;            // [B,H,DK,S]
  short* ctx = VTw + R_ * D_;           // [B,S,D]

  cvt_kernel<<<5376, 256, 0, stream>>>(x, wq, wk, wv, wo, xb, wb);
  qkv_gemm_kernel<<<dim3(6, 32, 3), 256, 0, stream>>>(xb, wb, bq, bk, bv, Qw, Kw, VTw);
  attn_kernel<<<dim3(16, 24), 256, 0, stream>>>(Qw, Kw, VTw, ctx);
  oproj_kernel<<<dim3(6, 32), 256, 0, stream>>>(ctx, wb + 3 * D_ * D_, bo, out);
}

// Round 2
// 121.518 us; speedup vs baseline: 2.2145x; 2.2145x over previous
//
#include <hip/hip_runtime.h>
#include <hip/hip_bf16.h>

#define B_   2
#define S_   2048
#define D_   768
#define H_   12
#define DK_  64
#define R_   (B_*S_)   // 4096 rows total

typedef __attribute__((ext_vector_type(8))) short short8;
typedef __attribute__((ext_vector_type(4))) float f32x4;

__device__ __forceinline__ short f2b(float f) {
  union { float f; unsigned u; } x; x.f = f;
  unsigned r = x.u + 0x7fffu + ((x.u >> 16) & 1u);
  return (short)(r >> 16);
}

__device__ __forceinline__ void gl_lds16(const short* g, short* l) {
  __builtin_amdgcn_global_load_lds(
      (const __attribute__((address_space(1))) void*)g,
      (__attribute__((address_space(3))) void*)l, 16, 0, 0);
}

// ---------------- fp32 -> bf16 conversion (x + 4 weights) ----------------
__global__ void cvt_kernel(const float* __restrict__ x,
                           const float* __restrict__ wq, const float* __restrict__ wk,
                           const float* __restrict__ wv, const float* __restrict__ wo,
                           short* __restrict__ xb, short* __restrict__ wb) {
  const int XQ = R_ * D_ / 4;   // float4 count for x
  const int WQ = D_ * D_ / 4;   // float4 count per weight
  int idx = blockIdx.x * blockDim.x + threadIdx.x;
  const float* src; short* dst; int off;
  if (idx < XQ) { src = x; dst = xb; off = idx; }
  else {
    int wi = idx - XQ; int w = wi / WQ; off = wi - w * WQ;
    if      (w == 0) { src = wq; dst = wb; }
    else if (w == 1) { src = wk; dst = wb + D_*D_; }
    else if (w == 2) { src = wv; dst = wb + 2*D_*D_; }
    else             { src = wo; dst = wb + 3*D_*D_; }
  }
  float4 v = ((const float4*)src)[off];
  short4 o;
  o.x = f2b(v.x); o.y = f2b(v.y); o.z = f2b(v.z); o.w = f2b(v.w);
  ((short4*)dst)[off] = o;
}

// ---------------- QKV projection: y = x @ W^T + b, head-major outputs ----------------
__launch_bounds__(256)
__global__ void qkv_gemm_kernel(const short* __restrict__ xb, const short* __restrict__ wb,
                                const float* __restrict__ bq, const float* __restrict__ bk,
                                const float* __restrict__ bv,
                                short* __restrict__ Qw, short* __restrict__ Kw,
                                short* __restrict__ VTw) {
  __shared__ short As[128 * 32];
  __shared__ short Bs[128 * 32];
  const int which = blockIdx.z;
  const short* W = wb + which * (D_ * D_);
  const float* bias = (which == 0) ? bq : (which == 1) ? bk : bv;
  const int n0 = blockIdx.x * 128, m0 = blockIdx.y * 128;
  const int t = threadIdx.x, l = t & 63, w = t >> 6;
  const int wr = w >> 1, wc = w & 1;

  f32x4 acc[4][4] = {};

  const int srow = t >> 2, sseg = (t & 3) * 8;

  for (int k0 = 0; k0 < D_; k0 += 32) {
    __syncthreads();
    gl_lds16(xb + (m0 + srow) * D_ + k0 + sseg,      &As[t * 8]);
    gl_lds16(xb + (m0 + 64 + srow) * D_ + k0 + sseg, &As[(t + 256) * 8]);
    gl_lds16(W  + (n0 + srow) * D_ + k0 + sseg,      &Bs[t * 8]);
    gl_lds16(W  + (n0 + 64 + srow) * D_ + k0 + sseg, &Bs[(t + 256) * 8]);
    __syncthreads();
    short8 a[4], b[4];
#pragma unroll
    for (int i = 0; i < 4; i++)
      a[i] = *(const short8*)&As[(wr * 64 + i * 16 + (l & 15)) * 32 + (l >> 4) * 8];
#pragma unroll
    for (int i = 0; i < 4; i++)
      b[i] = *(const short8*)&Bs[(wc * 64 + i * 16 + (l & 15)) * 32 + (l >> 4) * 8];
#pragma unroll
    for (int i = 0; i < 4; i++)
#pragma unroll
      for (int j = 0; j < 4; j++)
        acc[i][j] = __builtin_amdgcn_mfma_f32_16x16x32_bf16(a[i], b[j], acc[i][j], 0, 0, 0);
  }

#pragma unroll
  for (int i = 0; i < 4; i++) {
#pragma unroll
    for (int j2 = 0; j2 < 4; j2++) {
      int mm = m0 + wr * 64 + i * 16 + (l >> 4) * 4 + j2;
      int bidx = mm >> 11, s = mm & 2047;
#pragma unroll
      for (int nj = 0; nj < 4; nj++) {
        int e = n0 + wc * 64 + nj * 16 + (l & 15);
        float val = acc[i][nj][j2] + bias[e];
        int h = e >> 6, dk = e & 63;
        int bh = bidx * H_ + h;
        if (which == 0)      Qw[(bh * S_ + s) * DK_ + dk] = f2b(val * 0.125f);
        else if (which == 1) Kw[(bh * S_ + s) * DK_ + dk] = f2b(val);
        else                 VTw[(bh * DK_ + dk) * S_ + s] = f2b(val);
      }
    }
  }
}

// ---------------- flash attention v2 ----------------
// Grid (32, 24): 64 q-rows/block, 4 waves x 16 q-rows. KVBLK=64.
// Swapped QK^T: mfma(K,Q) -> lane holds full P-row for q = l&15.
// K/V staged in LDS via global_load_lds (linear dest, pre-swizzled SOURCE,
// XOR-swizzled reads), double buffered, T3 minimum-2-phase schedule.
#define KVB 64
__launch_bounds__(256)
__global__ void attn_kernel(const short* __restrict__ Qw, const short* __restrict__ Kw,
                            const short* __restrict__ VTw, short* __restrict__ ctx) {
  __shared__ short Ksh[2][KVB * DK_];   // [buf][k-row][dk] rows of 128B, source-swizzled
  __shared__ short Vsh[2][DK_ * KVB];   // [buf][d-row][s]  rows of 128B, source-swizzled
  __shared__ short Psh[4][16 * 72];     // per-wave P tile [q][k], row padded to 144B

  const int t = threadIdx.x, l = t & 63, w = t >> 6;
  const int bh = blockIdx.y;
  const int q0 = blockIdx.x * 64 + w * 16;
  const int bq = bh / H_, h = bh - bq * H_;
  const short* Qh = Qw + bh * S_ * DK_;
  const short* Kh = Kw + bh * S_ * DK_;
  const short* Vh = VTw + bh * DK_ * S_;
  short* pl = &Psh[w][0];

  // staging geometry: chunk i covers LDS elements [i*8, i*8+8); row r=i>>3, col-chunk c=i&7.
  // source chunk is (c ^ (r&7)) so that a swizzled READ sees linear data (rule #21).
  const int i0 = t,        r0 = i0 >> 3, c0 = i0 & 7;
  const int i1 = t + 256,  r1 = i1 >> 3, c1 = i1 & 7;
  const int koff0 = r0 * DK_ + ((c0 ^ (r0 & 7)) << 3);
  const int koff1 = r1 * DK_ + ((c1 ^ (r1 & 7)) << 3);
  const int voff0 = r0 * S_  + ((c0 ^ (r0 & 7)) << 3);
  const int voff1 = r1 * S_  + ((c1 ^ (r1 & 7)) << 3);

#define STAGE(buf, kt) do { \
    gl_lds16(Kh + (kt) * DK_ + koff0, &Ksh[buf][i0 * 8]); \
    gl_lds16(Kh + (kt) * DK_ + koff1, &Ksh[buf][i1 * 8]); \
    gl_lds16(Vh + (kt) + voff0,       &Vsh[buf][i0 * 8]); \
    gl_lds16(Vh + (kt) + voff1,       &Vsh[buf][i1 * 8]); \
  } while (0)

  // Q fragments in registers (pre-scaled by 1/8 at projection)
  short8 qf[2];
#pragma unroll
  for (int ks = 0; ks < 2; ks++)
    qf[ks] = *(const short8*)&Qh[(q0 + (l & 15)) * DK_ + ks * 32 + (l >> 4) * 8];

  f32x4 acc_o[4] = {};
  float m_run = -INFINITY, l_run = 0.f;

  STAGE(0, 0);
  __syncthreads();
  int cur = 0;

  for (int kt = 0; kt < S_; kt += KVB) {
    if (kt + KVB < S_) STAGE(cur ^ 1, kt + KVB);

    // ---- QK^T (swapped): A = K tile rows, B = Q. C[col=q=l&15][row=k] ----
    f32x4 acc_s[4] = {};
    __builtin_amdgcn_s_setprio(1);
#pragma unroll
    for (int ni = 0; ni < 4; ni++) {
#pragma unroll
      for (int ks = 0; ks < 2; ks++) {
        int r = (l & 15) + 16 * ni;
        int cc = (l >> 4) + 4 * ks;
        short8 kf = *(const short8*)&Ksh[cur][r * DK_ + ((cc ^ (r & 7)) << 3)];
        acc_s[ni] = __builtin_amdgcn_mfma_f32_16x16x32_bf16(kf, qf[ks], acc_s[ni], 0, 0, 0);
      }
    }
    __builtin_amdgcn_s_setprio(0);

    // ---- online softmax: lane owns P-row for q = l&15 (16 vals in-lane, 4 lane-groups) ----
    float mx = -INFINITY;
#pragma unroll
    for (int ni = 0; ni < 4; ni++)
#pragma unroll
      for (int j = 0; j < 4; j++) mx = fmaxf(mx, acc_s[ni][j]);
    mx = fmaxf(mx, __shfl_xor(mx, 16));
    mx = fmaxf(mx, __shfl_xor(mx, 32));
    float mnew = fmaxf(m_run, mx);
    float fac = __expf(m_run - mnew);
    m_run = mnew;
    float sum = 0.f;
#pragma unroll
    for (int ni = 0; ni < 4; ni++)
#pragma unroll
      for (int j = 0; j < 4; j++) {
        float p = __expf(acc_s[ni][j] - mnew);
        acc_s[ni][j] = p;
        sum += p;
      }
    sum += __shfl_xor(sum, 16);
    sum += __shfl_xor(sum, 32);
    l_run = l_run * fac + sum;

    // rescale acc_o: lane needs fac for q = (l>>4)*4+j (lives at lane q)
    float facj[4];
#pragma unroll
    for (int j = 0; j < 4; j++) facj[j] = __shfl(fac, ((l >> 4) << 2) + j);
#pragma unroll
    for (int nd = 0; nd < 4; nd++)
#pragma unroll
      for (int j = 0; j < 4; j++) acc_o[nd][j] *= facj[j];

    // ---- P -> LDS: packed short4 writes (k-contiguous), wave-private ----
#pragma unroll
    for (int ni = 0; ni < 4; ni++) {
      short4 pk;
      pk.x = f2b(acc_s[ni][0]); pk.y = f2b(acc_s[ni][1]);
      pk.z = f2b(acc_s[ni][2]); pk.w = f2b(acc_s[ni][3]);
      *(short4*)&pl[(l & 15) * 72 + (l >> 4) * 4 + 16 * ni] = pk;
    }

    // ---- PV: A = P[q][k], B = V^T[d][k]. C[col=d=l&15][row=q] ----
    __builtin_amdgcn_s_setprio(1);
#pragma unroll
    for (int ks = 0; ks < 2; ks++) {
      short8 pa = *(const short8*)&pl[(l & 15) * 72 + (l >> 4) * 8 + 32 * ks];
#pragma unroll
      for (int nd = 0; nd < 4; nd++) {
        int r = (l & 15) + 16 * nd;
        int cc = (l >> 4) + 4 * ks;
        short8 vf = *(const short8*)&Vsh[cur][r * KVB + ((cc ^ (r & 7)) << 3)];
        acc_o[nd] = __builtin_amdgcn_mfma_f32_16x16x32_bf16(pa, vf, acc_o[nd], 0, 0, 0);
      }
    }
    __builtin_amdgcn_s_setprio(0);

    __syncthreads();   // drains vmcnt: next tile staged; also WAR fence for buf^1
    cur ^= 1;
  }

  // ---- finalize: /l_run (lives at lane q), write ctx [B,S,D] bf16 ----
  float inv = 1.f / l_run;
  float invj[4];
#pragma unroll
  for (int j = 0; j < 4; j++) invj[j] = __shfl(inv, ((l >> 4) << 2) + j);
#pragma unroll
  for (int nd = 0; nd < 4; nd++)
#pragma unroll
    for (int j = 0; j < 4; j++) {
      int s = q0 + (l >> 4) * 4 + j;
      ctx[(bq * S_ + s) * D_ + h * DK_ + (l & 15) + 16 * nd] = f2b(acc_o[nd][j] * invj[j]);
    }
#undef STAGE
}

// ---------------- output projection: out = ctx @ Wo^T + bo (fp32 out) ----------------
__launch_bounds__(256)
__global__ void oproj_kernel(const short* __restrict__ ctx, const short* __restrict__ Wo,
                             const float* __restrict__ bo, float* __restrict__ out) {
  __shared__ short As[128 * 32];
  __shared__ short Bs[128 * 32];
  const int n0 = blockIdx.x * 128, m0 = blockIdx.y * 128;
  const int t = threadIdx.x, l = t & 63, w = t >> 6;
  const int wr = w >> 1, wc = w & 1;

  f32x4 acc[4][4] = {};
  const int srow = t >> 2, sseg = (t & 3) * 8;

  for (int k0 = 0; k0 < D_; k0 += 32) {
    __syncthreads();
    gl_lds16(ctx + (m0 + srow) * D_ + k0 + sseg,      &As[t * 8]);
    gl_lds16(ctx + (m0 + 64 + srow) * D_ + k0 + sseg, &As[(t + 256) * 8]);
    gl_lds16(Wo  + (n0 + srow) * D_ + k0 + sseg,      &Bs[t * 8]);
    gl_lds16(Wo  + (n0 + 64 + srow) * D_ + k0 + sseg, &Bs[(t + 256) * 8]);
    __syncthreads();
    short8 a[4], b[4];
#pragma unroll
    for (int i = 0; i < 4; i++)
      a[i] = *(const short8*)&As[(wr * 64 + i * 16 + (l & 15)) * 32 + (l >> 4) * 8];
#pragma unroll
    for (int i = 0; i < 4; i++)
      b[i] = *(const short8*)&Bs[(wc * 64 + i * 16 + (l & 15)) * 32 + (l >> 4) * 8];
#pragma unroll
    for (int i = 0; i < 4; i++)
#pragma unroll
      for (int j = 0; j < 4; j++)
        acc[i][j] = __builtin_amdgcn_mfma_f32_16x16x32_bf16(a[i], b[j], acc[i][j], 0, 0, 0);
  }

#pragma unroll
  for (int i = 0; i < 4; i++) {
#pragma unroll
    for (int j2 = 0; j2 < 4; j2++) {
      int mm = m0 + wr * 64 + i * 16 + (l >> 4) * 4 + j2;
#pragma unroll
      for (int nj = 0; nj < 4; nj++) {
        int e = n0 + wc * 64 + nj * 16 + (l & 15);
        out[mm * D_ + e] = acc[i][nj][j2] + bo[e];
      }
    }
  }
}

extern "C" void kernel_launch(void* const* d_in, const int* in_sizes, int n_in,
                              void* d_out, int out_size, void* d_ws, size_t ws_size,
                              hipStream_t stream) {
  (void)in_sizes; (void)n_in; (void)out_size; (void)ws_size;
  const float* x  = (const float*)d_in[0];
  const float* wq = (const float*)d_in[1];
  const float* bq = (const float*)d_in[2];
  const float* wk = (const float*)d_in[3];
  const float* bk = (const float*)d_in[4];
  const float* wv = (const float*)d_in[5];
  const float* bv = (const float*)d_in[6];
  const float* wo = (const float*)d_in[7];
  const float* bo = (const float*)d_in[8];
  float* out = (float*)d_out;

  short* xb  = (short*)d_ws;            // R*D bf16
  short* wb  = xb + R_ * D_;            // 4*D*D bf16 (q,k,v,o)
  short* Qw  = wb + 4 * D_ * D_;        // [B,H,S,DK]
  short* Kw  = Qw + R_ * D_;            // [B,H,S,DK]
  short* VTw = Kw + R_ * D_;            // [B,H,DK,S]
  short* ctx = VTw + R_ * D_;           // [B,S,D]

  cvt_kernel<<<5376, 256, 0, stream>>>(x, wq, wk, wv, wo, xb, wb);
  qkv_gemm_kernel<<<dim3(6, 32, 3), 256, 0, stream>>>(xb, wb, bq, bk, bv, Qw, Kw, VTw);
  attn_kernel<<<dim3(32, 24), 256, 0, stream>>>(Qw, Kw, VTw, ctx);
  oproj_kernel<<<dim3(6, 32), 256, 0, stream>>>(ctx, wb + 3 * D_ * D_, bo, out);
}